// Round 17
// baseline (52.525 us; speedup 1.0000x reference)
//
#include <hip/hip_runtime.h>

typedef __attribute__((ext_vector_type(8))) short bf16x8;
typedef __attribute__((ext_vector_type(4))) float f32x4;

namespace {
constexpr int NB=8, N1=4096, N2=1024, F1=128, F2=256, H2=256;
constexpr int TM=32;
constexpr float SLOPE=0.2f, EPSD=1e-10f;
constexpr size_t WS_W1=0;                     // 192 KB
constexpr size_t WS_W2=196608;                // 128 KB
constexpr int XT_STRIDE=784;
constexpr int H_STRIDE=528;
// dynamic LDS regions (disjoint, total 64512 <= 65536)
constexpr int L_XQ=0;          // 16384: xyz2 (x,y,z,sq)
constexpr int L_CAND=16384;    // 6144:  256 cand * 24B
constexpr int L_XT=22528;      // 25088: X tile
constexpr int L_H=47616;       // 16896: h tile
constexpr int LDS_BYTES=64512;
}

__device__ __forceinline__ unsigned short f2bf(float f){
  union{float f; unsigned u;} v; v.f=f;
  unsigned r = v.u + 0x7FFFu + ((v.u>>16)&1u);   // RNE
  return (unsigned short)(r>>16);
}
__device__ __forceinline__ unsigned cvt_pk_bf16(float lo, float hi){
  unsigned r;
  asm("v_cvt_pk_bf16_f32 %0, %1, %2" : "=v"(r) : "v"(lo), "v"(hi));
  return r;
}
__device__ __forceinline__ float lrelu(float x){ return x>=0.f? x : SLOPE*x; }

__global__ __launch_bounds__(256)
void transform_w(const float* __restrict__ W1, const float* __restrict__ W2,
                 char* __restrict__ ws)
{
  int id = blockIdx.x*256 + threadIdx.x;
  const float* src; size_t dst;
  if (id < 12288) {                             // W1: 192 frags
    int frag = id >> 6, ln = id & 63;
    int n = (((frag>>2)&3)*64) + ((frag&3)*16) + (ln & 15);
    int k0 = (frag>>4)*32 + (ln>>4)*8;
    src = W1 + (size_t)k0*256 + n;
    dst = WS_W1 + (size_t)frag*1024 + ln*16;
  } else if (id < 20480) {                      // W2: 128 frags
    int fid = id - 12288, frag = fid >> 6, ln = fid & 63;
    int n = (((frag>>2)&3)*64) + ((frag&3)*16) + (ln & 15);
    int k0 = (frag>>4)*32 + (ln>>4)*8;
    src = W2 + (size_t)k0*256 + n;
    dst = WS_W2 + (size_t)frag*1024 + ln*16;
  } else return;
  unsigned u[4];
  #pragma unroll
  for (int p=0;p<4;++p)
    u[p] = (unsigned)f2bf(src[(2*p)*256]) | ((unsigned)f2bf(src[(2*p+1)*256])<<16);
  *(uint4*)(ws + dst) = make_uint4(u[0],u[1],u[2],u[3]);
}

// 2-tile pipelined block: tile0 = rows g*32, tile1 = g*32+2048 (same batch).
// tile1's scan interleaved into tile0's GEMM1 MFMA shadow. grid 512.
__global__ __launch_bounds__(256, 2)
void fp_mfma(const float* __restrict__ xyz1, const float* __restrict__ xyz2,
             const float* __restrict__ p1,   const float* __restrict__ p2,
             const char* __restrict__ ws,
             const float* __restrict__ b1,   const float* __restrict__ b2,
             float* __restrict__ out)
{
  extern __shared__ __align__(16) char smem[];
  __shared__ float s_w[TM][4];
  __shared__ int   s_idx[TM][4];

  const int t = threadIdx.x;
  const int b = blockIdx.x & 7;                // batch == XCD
  const int g = blockIdx.x >> 3;               // 0..63
  const int row0a = g * TM;
  const int row0b = row0a + 2048;
  const int lane = t & 63, wv = t >> 6;
  const int lrow = lane & 15, lg = lane >> 4;
  const int nq = wv;

  // ---- P0: stage xyz2 -> LDS ----
  {
    float4* xq = (float4*)(smem + L_XQ);
    const float* xz = xyz2 + (size_t)b*N2*3;
    for (int j = t; j < N2; j += 256) {
      float x = xz[3*j], y = xz[3*j+1], z = xz[3*j+2];
      xq[j] = make_float4(x, y, z, x*x + y*y + z*z);
    }
  }
  __syncthreads();

  const int srow = lane & 31, sslice = wv*2 + (lane >> 5);

  // ---- P1: scan tile0 ----
  {
    const float4* xq = (const float4*)(smem + L_XQ);
    const float* x1 = xyz1 + ((size_t)b*N1 + row0a + srow)*3;
    const float px=x1[0], py=x1[1], pz=x1[2];
    const float sq1 = px*px + py*py + pz*pz;
    float d0=3.4e38f, d1=3.4e38f, d2=3.4e38f;
    int i0=0, i1=0, i2=0;
    const int j0 = sslice*128;
    #pragma unroll 8
    for (int j = j0; j < j0+128; ++j) {
      float4 q = xq[j];
      float dot = px*q.x + py*q.y + pz*q.z;
      float d = fmaf(-2.f, dot, sq1 + q.w);
      bool c0 = d < d0, c1 = d < d1, c2 = d < d2;
      i2 = c1 ? i1 : (c2 ? j : i2);
      i1 = c0 ? i0 : (c1 ? j : i1);
      i0 = c0 ? j  : i0;
      d2 = __builtin_amdgcn_fmed3f(d, d1, d2);
      d1 = __builtin_amdgcn_fmed3f(d, d0, d1);
      d0 = fminf(d, d0);
    }
    char* p = smem + L_CAND + (sslice*32 + srow)*24;
    *(float2*)p = make_float2(d0, d1);
    *(float*)(p+8) = d2;
    ((int*)p)[3]=i0; ((int*)p)[4]=i1; ((int*)p)[5]=i2;
  }
  __syncthreads();

  auto mergeCand = [&](){
    if (t < TM) {
      float d0=3.4e38f,d1=3.4e38f,d2=3.4e38f; int i0=0,i1=0,i2=0;
      for (int p=0;p<8;++p){
        const char* c2 = smem + L_CAND + (p*32 + t)*24;
        float2 dd = *(const float2*)c2;
        float dc[3] = {dd.x, dd.y, *(const float*)(c2+8)};
        int ic[3] = {((const int*)c2)[3], ((const int*)c2)[4], ((const int*)c2)[5]};
        #pragma unroll
        for (int c=0;c<3;++c){
          float d = dc[c]; int ii = ic[c];
          if (d < d2) {
            if (d < d1) { d2=d1; i2=i1;
              if (d < d0) { d1=d0; i1=i0; d0=d; i0=ii; } else { d1=d; i1=ii; }
            } else { d2=d; i2=ii; }
          }
        }
      }
      d0=fmaxf(d0,EPSD); d1=fmaxf(d1,EPSD); d2=fmaxf(d2,EPSD);
      float w0=1.f/d0, w1=1.f/d1, w2=1.f/d2, inv=1.f/(w0+w1+w2);
      s_w[t][0]=w0*inv; s_w[t][1]=w1*inv; s_w[t][2]=w2*inv;
      s_idx[t][0]=i0; s_idx[t][1]=i1; s_idx[t][2]=i2;
    }
  };

  // ---- P2: merge0 ----
  mergeCand();
  __syncthreads();

  // ===== Phase-B machinery =====
  const int rr = t >> 3, qq = t & 7;
  float w0_, w1_, w2_; int g0_, g1_, g2_;
  const float* p1r = p1;
  auto readWg = [&](int rowbase){
    w0_=s_w[rr][0]; w1_=s_w[rr][1]; w2_=s_w[rr][2];
    g0_=s_idx[rr][0]; g1_=s_idx[rr][1]; g2_=s_idx[rr][2];
    p1r = p1 + ((size_t)b*N1 + rowbase + rr)*F1;
  };
  const char* wsW1 = ws + WS_W1;
  const char* wsW2 = ws + WS_W2;
  const float* p2b = p2 + (size_t)b*N2*F2;
  char* Xt = smem + L_XT;
  char* hB = smem + L_H;

  auto issueAny = [&](int kcg, float4* gq){
    if (kcg < 4) {
      const int k0 = kcg*64 + qq*8;
      const float4* q0 = (const float4*)(p2b + (size_t)g0_*F2 + k0);
      const float4* q1 = (const float4*)(p2b + (size_t)g1_*F2 + k0);
      const float4* q2 = (const float4*)(p2b + (size_t)g2_*F2 + k0);
      gq[0]=q0[0]; gq[1]=q0[1]; gq[2]=q1[0]; gq[3]=q1[1]; gq[4]=q2[0]; gq[5]=q2[1];
    } else {
      const float4* q = (const float4*)(p1r + (kcg*64 + qq*8 - F2));
      gq[0]=q[0]; gq[1]=q[1];
    }
  };
  auto writeAny = [&](int kcg, const float4* gq){
    float v[8];
    if (kcg < 4) {
      #pragma unroll
      for (int p=0;p<2;++p){
        v[4*p+0] = fmaf(w2_, gq[4+p].x, fmaf(w1_, gq[2+p].x, w0_*gq[p].x));
        v[4*p+1] = fmaf(w2_, gq[4+p].y, fmaf(w1_, gq[2+p].y, w0_*gq[p].y));
        v[4*p+2] = fmaf(w2_, gq[4+p].z, fmaf(w1_, gq[2+p].z, w0_*gq[p].z));
        v[4*p+3] = fmaf(w2_, gq[4+p].w, fmaf(w1_, gq[2+p].w, w0_*gq[p].w));
      }
    } else {
      #pragma unroll
      for (int p=0;p<2;++p){
        v[4*p+0]=gq[p].x; v[4*p+1]=gq[p].y; v[4*p+2]=gq[p].z; v[4*p+3]=gq[p].w;
      }
    }
    unsigned u[4];
    #pragma unroll
    for (int p=0;p<4;++p) u[p] = cvt_pk_bf16(v[2*p], v[2*p+1]);
    *(uint4*)(Xt + rr*XT_STRIDE + (kcg*8 + qq)*16) = make_uint4(u[0],u[1],u[2],u[3]);
  };
  auto buildX = [&](){
    float4 ga[6], gb[6];
    issueAny(0, ga); issueAny(1, gb);
    writeAny(0, ga); issueAny(2, ga);
    writeAny(1, gb); issueAny(3, gb);
    writeAny(2, ga); issueAny(4, ga);
    writeAny(3, gb); issueAny(5, gb);
    writeAny(4, ga); writeAny(5, gb);
  };
  auto loadW = [&](const char* base, int s, bf16x8* dst){
    #pragma unroll
    for (int nt=0;nt<4;++nt)
      dst[nt] = *(const bf16x8*)(base + ((s*16 + nq*4 + nt)<<10) + lane*16);
  };
  auto gemmStep = [&](int s, const bf16x8* bw, f32x4 (&ac)[2][4],
                      const char* Ab, int stride){
    bf16x8 af[2];
    #pragma unroll
    for (int mt=0;mt<2;++mt)
      af[mt] = *(const bf16x8*)(Ab + (mt*16+lrow)*stride + (s*4+lg)*16);
    #pragma unroll
    for (int mt=0;mt<2;++mt)
      #pragma unroll
      for (int nt=0;nt<4;++nt)
        ac[mt][nt] = __builtin_amdgcn_mfma_f32_16x16x32_bf16(af[mt], bw[nt], ac[mt][nt], 0,0,0);
  };
  auto zeroAcc = [&](f32x4 (&ac)[2][4]){
    #pragma unroll
    for (int mt=0;mt<2;++mt)
      #pragma unroll
      for (int nt=0;nt<4;++nt) ac[mt][nt] = (f32x4){0.f,0.f,0.f,0.f};
  };
  auto hconvert = [&](f32x4 (&ac)[2][4]){
    float bb[4];
    #pragma unroll
    for (int nt=0;nt<4;++nt) bb[nt] = b1[nq*64 + nt*16 + lrow];
    #pragma unroll
    for (int mt=0;mt<2;++mt)
      #pragma unroll
      for (int rg=0;rg<4;++rg) {
        const int row = mt*16 + lg*4 + rg;
        char* hb = hB + row*H_STRIDE + (nq*64 + lrow)*2;
        float v0 = lrelu(ac[mt][0][rg] + bb[0]);
        float v1 = lrelu(ac[mt][1][rg] + bb[1]);
        float v2 = lrelu(ac[mt][2][rg] + bb[2]);
        float v3 = lrelu(ac[mt][3][rg] + bb[3]);
        unsigned pA = cvt_pk_bf16(v0, v1), pB = cvt_pk_bf16(v2, v3);
        *(short*)(hb)      = (short)pA;
        *(short*)(hb + 32) = (short)(pA >> 16);
        *(short*)(hb + 64) = (short)pB;
        *(short*)(hb + 96) = (short)(pB >> 16);
      }
  };
  auto gemm2 = [&](f32x4 (&ac2)[2][4], bf16x8* bwA, bf16x8* bwB, bf16x8* bwC){
    zeroAcc(ac2);
    gemmStep(0, bwA, ac2, hB, H_STRIDE); loadW(wsW2, 3, bwA);
    gemmStep(1, bwB, ac2, hB, H_STRIDE); loadW(wsW2, 4, bwB);
    gemmStep(2, bwC, ac2, hB, H_STRIDE); loadW(wsW2, 5, bwC);
    gemmStep(3, bwA, ac2, hB, H_STRIDE); loadW(wsW2, 6, bwA);
    gemmStep(4, bwB, ac2, hB, H_STRIDE); loadW(wsW2, 7, bwB);
    gemmStep(5, bwC, ac2, hB, H_STRIDE);
    gemmStep(6, bwA, ac2, hB, H_STRIDE);
    gemmStep(7, bwB, ac2, hB, H_STRIDE);
  };
  auto epilogue = [&](f32x4 (&ac2)[2][4], int rowbase){
    float bb[4];
    #pragma unroll
    for (int nt=0;nt<4;++nt) bb[nt] = b2[nq*64 + nt*16 + lrow];
    float* ob = out + ((size_t)b*N1 + rowbase) * H2;
    #pragma unroll
    for (int mt=0;mt<2;++mt)
      #pragma unroll
      for (int rg=0;rg<4;++rg) {
        const int row = mt*16 + lg*4 + rg;
        #pragma unroll
        for (int nt=0;nt<4;++nt) {
          const int col = nq*64 + nt*16 + lrow;
          ob[(size_t)row*H2 + col] = lrelu(ac2[mt][nt][rg] + bb[nt]);
        }
      }
  };

  // scan1 persistent state
  float s1px, s1py, s1pz, s1sq;
  float s1d0=3.4e38f, s1d1=3.4e38f, s1d2=3.4e38f;
  int s1i0=0, s1i1=0, s1i2=0;
  auto scanChunk = [&](int c){
    const float4* xq = (const float4*)(smem + L_XQ);
    const int jb = sslice*128 + c*16;
    #pragma unroll 4
    for (int j = jb; j < jb+16; ++j) {
      float4 q = xq[j];
      float dot = s1px*q.x + s1py*q.y + s1pz*q.z;
      float d = fmaf(-2.f, dot, s1sq + q.w);
      bool c0 = d < s1d0, c1 = d < s1d1, c2 = d < s1d2;
      s1i2 = c1 ? s1i1 : (c2 ? j : s1i2);
      s1i1 = c0 ? s1i0 : (c1 ? j : s1i1);
      s1i0 = c0 ? j    : s1i0;
      s1d2 = __builtin_amdgcn_fmed3f(d, s1d1, s1d2);
      s1d1 = __builtin_amdgcn_fmed3f(d, s1d0, s1d1);
      s1d0 = fminf(d, s1d0);
    }
  };

  f32x4 acc[2][4], acc2[2][4];
  bf16x8 bwA[4], bwB[4], bwC[4];

  // ---- P3: tile0 X build + W prefetch + scan1 init ----
  readWg(row0a);
  loadW(wsW1, 0, bwA); loadW(wsW1, 1, bwB); loadW(wsW1, 2, bwC);
  buildX();
  {
    const float* x1 = xyz1 + ((size_t)b*N1 + row0b + srow)*3;
    s1px=x1[0]; s1py=x1[1]; s1pz=x1[2];
    s1sq = s1px*s1px + s1py*s1py + s1pz*s1pz;
  }
  __syncthreads();

  // ---- P4: GEMM1-0 (12 steps) interleaved with scan1 (8 x 16j chunks) ----
  zeroAcc(acc);
  #pragma unroll
  for (int u=0; u<4; ++u) {
    gemmStep(3*u,   bwA, acc, Xt, XT_STRIDE);
    if (u<3) loadW(wsW1, 3*u+3, bwA); else loadW(wsW2, 0, bwA);
    scanChunk(2*u);
    gemmStep(3*u+1, bwB, acc, Xt, XT_STRIDE);
    if (u<3) loadW(wsW1, 3*u+4, bwB); else loadW(wsW2, 1, bwB);
    scanChunk(2*u+1);
    gemmStep(3*u+2, bwC, acc, Xt, XT_STRIDE);
    if (u<3) loadW(wsW1, 3*u+5, bwC); else loadW(wsW2, 2, bwC);
  }

  // ---- P5: write cand1 ----
  {
    char* p = smem + L_CAND + (sslice*32 + srow)*24;
    *(float2*)p = make_float2(s1d0, s1d1);
    *(float*)(p+8) = s1d2;
    ((int*)p)[3]=s1i0; ((int*)p)[4]=s1i1; ((int*)p)[5]=s1i2;
  }
  __syncthreads();

  // ---- P6: h0 convert + merge1 ----
  hconvert(acc);
  mergeCand();
  __syncthreads();

  // ---- P7: GEMM2-0 + epilogue0 ----
  readWg(row0b);
  gemm2(acc2, bwA, bwB, bwC);
  epilogue(acc2, row0a);

  // ---- P8: tile1 X build + W1 prefetch ----
  buildX();
  loadW(wsW1, 0, bwA); loadW(wsW1, 1, bwB); loadW(wsW1, 2, bwC);
  __syncthreads();

  // ---- P9: GEMM1-1 (12 steps, plain) ----
  zeroAcc(acc);
  #pragma unroll
  for (int u=0; u<4; ++u) {
    gemmStep(3*u,   bwA, acc, Xt, XT_STRIDE);
    if (u<3) loadW(wsW1, 3*u+3, bwA); else loadW(wsW2, 0, bwA);
    gemmStep(3*u+1, bwB, acc, Xt, XT_STRIDE);
    if (u<3) loadW(wsW1, 3*u+4, bwB); else loadW(wsW2, 1, bwB);
    gemmStep(3*u+2, bwC, acc, Xt, XT_STRIDE);
    if (u<3) loadW(wsW1, 3*u+5, bwC); else loadW(wsW2, 2, bwC);
  }

  // ---- P10: h1 convert ----
  __syncthreads();            // all threads done reading h0 long ago; acc ready
  hconvert(acc);
  __syncthreads();

  // ---- P11: GEMM2-1 + epilogue1 ----
  gemm2(acc2, bwA, bwB, bwC);
  epilogue(acc2, row0b);
}

extern "C" void kernel_launch(void* const* d_in, const int* in_sizes, int n_in,
                              void* d_out, int out_size, void* d_ws, size_t ws_size,
                              hipStream_t stream) {
  const float* xyz1    = (const float*)d_in[0];
  const float* xyz2    = (const float*)d_in[1];
  const float* points1 = (const float*)d_in[2];
  const float* points2 = (const float*)d_in[3];
  const float* W1      = (const float*)d_in[4];
  const float* b1      = (const float*)d_in[5];
  const float* W2      = (const float*)d_in[6];
  const float* b2      = (const float*)d_in[7];
  float* out = (float*)d_out;

  hipLaunchKernelGGL(transform_w, dim3(80), dim3(256), 0, stream, W1, W2, (char*)d_ws);
  hipLaunchKernelGGL(fp_mfma, dim3(NB * (N1 / TM / 2)), dim3(256), LDS_BYTES, stream,
                     xyz1, xyz2, points1, points2, (const char*)d_ws, b1, b2, out);
}

// Round 18
// 43.513 us; speedup vs baseline: 1.2071x; 1.2071x over previous
//
#include <hip/hip_runtime.h>

typedef __attribute__((ext_vector_type(8))) short bf16x8;
typedef __attribute__((ext_vector_type(4))) float f32x4;

namespace {
constexpr int NB=8, N1=4096, N2=1024, F1=128, F2=256, H2=256;
constexpr int TM=32;
constexpr float SLOPE=0.2f, EPSD=1e-10f;
constexpr size_t WS_W1=0;                     // 192 KB (12 steps * 16 frags * 1KB)
constexpr size_t WS_W2=196608;                // 128 KB
constexpr int XT_STRIDE=784;   // 48 slots*16B + 16B pad
constexpr int H_STRIDE=528;    // 512B row + 16B pad
}

__device__ __forceinline__ unsigned short f2bf(float f){
  union{float f; unsigned u;} v; v.f=f;
  unsigned r = v.u + 0x7FFFu + ((v.u>>16)&1u);   // RNE
  return (unsigned short)(r>>16);
}
// packed RNE f32x2 -> bf16x2 (bit-identical to f2bf; verified R12/R14-R16)
__device__ __forceinline__ unsigned cvt_pk_bf16(float lo, float hi){
  unsigned r;
  asm("v_cvt_pk_bf16_f32 %0, %1, %2" : "=v"(r) : "v"(lo), "v"(hi));
  return r;
}
__device__ __forceinline__ float lrelu(float x){ return x>=0.f? x : SLOPE*x; }

// ===== W1/W2 -> bf16 frag-linear: frag = s*16 + nq*4 + nt; lane ln holds 8
// k-bf16 for n = nq*64+nt*16+(ln&15), k0 = s*32+(ln>>4)*8 =====
__global__ __launch_bounds__(256)
void transform_w(const float* __restrict__ W1, const float* __restrict__ W2,
                 char* __restrict__ ws)
{
  int id = blockIdx.x*256 + threadIdx.x;
  const float* src; size_t dst;
  if (id < 12288) {                             // W1: 192 frags
    int frag = id >> 6, ln = id & 63;
    int n = (((frag>>2)&3)*64) + ((frag&3)*16) + (ln & 15);
    int k0 = (frag>>4)*32 + (ln>>4)*8;
    src = W1 + (size_t)k0*256 + n;
    dst = WS_W1 + (size_t)frag*1024 + ln*16;
  } else if (id < 20480) {                      // W2: 128 frags
    int fid = id - 12288, frag = fid >> 6, ln = fid & 63;
    int n = (((frag>>2)&3)*64) + ((frag&3)*16) + (ln & 15);
    int k0 = (frag>>4)*32 + (ln>>4)*8;
    src = W2 + (size_t)k0*256 + n;
    dst = WS_W2 + (size_t)frag*1024 + ln*16;
  } else return;
  unsigned u[4];
  #pragma unroll
  for (int p=0;p<4;++p)
    u[p] = (unsigned)f2bf(src[(2*p)*256]) | ((unsigned)f2bf(src[(2*p+1)*256])<<16);
  *(uint4*)(ws + dst) = make_uint4(u[0],u[1],u[2],u[3]);
}

// Champion config (R16, 43.7 us): TM=32, 256 threads, grid 1024, 4 blocks/CU.
// Lessons encoded: no VGPR cap below ~96 natural use (R4/R6); scan from LDS
// (R10 vs R9 +3us); W from global in frag-linear order, reg-dbuf dist-3;
// cvt_pk_bf16 packing (R16, -0.6us); barrier-free GEMM K-loops.
__global__ __launch_bounds__(256, 2)
void fp_mfma(const float* __restrict__ xyz1, const float* __restrict__ xyz2,
             const float* __restrict__ p1,   const float* __restrict__ p2,
             const char* __restrict__ ws,
             const float* __restrict__ b1,   const float* __restrict__ b2,
             float* __restrict__ out)
{
  __shared__ __align__(16) char smem[25088];   // xq 16K + cand 8K; reused: Xt/h
  __shared__ float s_w[TM][4];
  __shared__ int   s_idx[TM][4];

  const int t = threadIdx.x;
  const int b = blockIdx.x & 7;                // batch == XCD
  const int row0 = (blockIdx.x >> 3) * TM;
  const int lane = t & 63, wv = t >> 6;
  const int lrow = lane & 15, lg = lane >> 4;
  const int nq = wv;

  // ===== Phase A: stage xyz2 -> LDS (x,y,z,sq), then 3-NN scan from LDS =====
  {
    float4* xq = (float4*)smem;                // [0, 16384)
    char* cand = smem + 16384;                 // [16384, 24576)
    const float* xz = xyz2 + (size_t)b*N2*3;
    for (int j = t; j < N2; j += 256) {
      float x = xz[3*j], y = xz[3*j+1], z = xz[3*j+2];
      xq[j] = make_float4(x, y, z, x*x + y*y + z*z);
    }
    __syncthreads();
    {
      const int row = lane & 31, slice = wv*2 + (lane >> 5);  // LDS broadcast reads
      const float* x1 = xyz1 + ((size_t)b*N1 + row0 + row)*3;
      const float px=x1[0], py=x1[1], pz=x1[2];
      const float sq1 = px*px + py*py + pz*pz;
      float d0=3.4e38f, d1=3.4e38f, d2=3.4e38f;
      int i0=0, i1=0, i2=0;
      const int j0 = slice*128;
      #pragma unroll 8
      for (int j = j0; j < j0+128; ++j) {
        float4 q = xq[j];
        float dot = px*q.x + py*q.y + pz*q.z;
        float d = fmaf(-2.f, dot, sq1 + q.w);
        bool c0 = d < d0, c1 = d < d1, c2 = d < d2;
        i2 = c1 ? i1 : (c2 ? j : i2);
        i1 = c0 ? i0 : (c1 ? j : i1);
        i0 = c0 ? j  : i0;
        d2 = __builtin_amdgcn_fmed3f(d, d1, d2);
        d1 = __builtin_amdgcn_fmed3f(d, d0, d1);
        d0 = fminf(d, d0);
      }
      float* cd = (float*)(cand + (slice*32 + row)*32);
      cd[0]=d0; cd[1]=d1; cd[2]=d2;
      ((int*)cd)[4]=i0; ((int*)cd)[5]=i1; ((int*)cd)[6]=i2;
    }
    __syncthreads();
    if (t < TM) {                              // merge 8 slices, j-ascending
      const char* cand_ = smem + 16384;
      float d0=3.4e38f,d1=3.4e38f,d2=3.4e38f; int i0=0,i1=0,i2=0;
      for (int p=0;p<8;++p){
        const float* cd = (const float*)(cand_ + (p*32 + t)*32);
        for (int c=0;c<3;++c){
          float d = cd[c]; int ii = ((const int*)cd)[4+c];
          if (d < d2) {
            if (d < d1) { d2=d1; i2=i1;
              if (d < d0) { d1=d0; i1=i0; d0=d; i0=ii; } else { d1=d; i1=ii; }
            } else { d2=d; i2=ii; }
          }
        }
      }
      d0=fmaxf(d0,EPSD); d1=fmaxf(d1,EPSD); d2=fmaxf(d2,EPSD);
      float w0=1.f/d0, w1=1.f/d1, w2=1.f/d2, inv=1.f/(w0+w1+w2);
      s_w[t][0]=w0*inv; s_w[t][1]=w1*inv; s_w[t][2]=w2*inv;
      s_idx[t][0]=i0; s_idx[t][1]=i1; s_idx[t][2]=i2;
    }
    __syncthreads();
  }

  // ===== Phase B =====
  const int rr = t >> 3, qq = t & 7;           // X build: 8 thr/row, 6 chunks
  const float w0_=s_w[rr][0], w1_=s_w[rr][1], w2_=s_w[rr][2];
  const int g0=s_idx[rr][0], g1=s_idx[rr][1], g2=s_idx[rr][2];
  const char* wsW1 = ws + WS_W1;
  const char* wsW2 = ws + WS_W2;
  const float* p2b = p2 + (size_t)b*N2*F2;
  const float* p1r = p1 + ((size_t)b*N1 + row0 + rr)*F1;

  auto issueAny = [&](int kcg, float4* g){
    if (kcg < 4) {
      const int k0 = kcg*64 + qq*8;
      const float4* q0 = (const float4*)(p2b + (size_t)g0*F2 + k0);
      const float4* q1 = (const float4*)(p2b + (size_t)g1*F2 + k0);
      const float4* q2 = (const float4*)(p2b + (size_t)g2*F2 + k0);
      g[0]=q0[0]; g[1]=q0[1]; g[2]=q1[0]; g[3]=q1[1]; g[4]=q2[0]; g[5]=q2[1];
    } else {
      const float4* q = (const float4*)(p1r + (kcg*64 + qq*8 - F2));
      g[0]=q[0]; g[1]=q[1];
    }
  };
  auto writeAny = [&](int kcg, const float4* g){
    float v[8];
    if (kcg < 4) {
      #pragma unroll
      for (int p=0;p<2;++p){
        v[4*p+0] = fmaf(w2_, g[4+p].x, fmaf(w1_, g[2+p].x, w0_*g[p].x));
        v[4*p+1] = fmaf(w2_, g[4+p].y, fmaf(w1_, g[2+p].y, w0_*g[p].y));
        v[4*p+2] = fmaf(w2_, g[4+p].z, fmaf(w1_, g[2+p].z, w0_*g[p].z));
        v[4*p+3] = fmaf(w2_, g[4+p].w, fmaf(w1_, g[2+p].w, w0_*g[p].w));
      }
    } else {
      #pragma unroll
      for (int p=0;p<2;++p){
        v[4*p+0]=g[p].x; v[4*p+1]=g[p].y; v[4*p+2]=g[p].z; v[4*p+3]=g[p].w;
      }
    }
    unsigned u[4];
    #pragma unroll
    for (int p=0;p<4;++p) u[p] = cvt_pk_bf16(v[2*p], v[2*p+1]);
    *(uint4*)(smem + rr*XT_STRIDE + (kcg*8 + qq)*16) = make_uint4(u[0],u[1],u[2],u[3]);
  };
  auto loadW = [&](const char* base, int s, bf16x8* dst){
    #pragma unroll
    for (int nt=0;nt<4;++nt)
      dst[nt] = *(const bf16x8*)(base + ((s*16 + nq*4 + nt)<<10) + lane*16);
  };
  auto gemmStep = [&](int s, const bf16x8* bw, f32x4 (&ac)[2][4],
                      const char* Ab, int stride){
    bf16x8 af[2];
    #pragma unroll
    for (int mt=0;mt<2;++mt)
      af[mt] = *(const bf16x8*)(Ab + (mt*16+lrow)*stride + (s*4+lg)*16);
    #pragma unroll
    for (int mt=0;mt<2;++mt)
      #pragma unroll
      for (int nt=0;nt<4;++nt)
        ac[mt][nt] = __builtin_amdgcn_mfma_f32_16x16x32_bf16(af[mt], bw[nt], ac[mt][nt], 0,0,0);
  };

  f32x4 acc[2][4];
  #pragma unroll
  for (int mt=0;mt<2;++mt)
    #pragma unroll
    for (int nt=0;nt<4;++nt) acc[mt][nt] = (f32x4){0.f,0.f,0.f,0.f};

  // ---- W steps 0..2 prefetch FIRST (L2 latency hides under X build) ----
  bf16x8 bwA[4], bwB[4], bwC[4];
  loadW(wsW1, 0, bwA);
  loadW(wsW1, 1, bwB);
  loadW(wsW1, 2, bwC);

  // ---- build full X tile (32 x 384), depth-2 gather pipeline ----
  float4 ga[6], gb[6];
  issueAny(0, ga); issueAny(1, gb);
  writeAny(0, ga); issueAny(2, ga);
  writeAny(1, gb); issueAny(3, gb);
  writeAny(2, ga); issueAny(4, ga);
  writeAny(3, gb); issueAny(5, gb);
  writeAny(4, ga); writeAny(5, gb);
  __syncthreads();

  // ---- GEMM1: 12 K32 steps, no internal barriers, W prefetch distance 3 ----
  #pragma unroll
  for (int u=0; u<4; ++u) {
    gemmStep(3*u,   bwA, acc, smem, XT_STRIDE);
    if (u<3) loadW(wsW1, 3*u+3, bwA); else loadW(wsW2, 0, bwA);
    gemmStep(3*u+1, bwB, acc, smem, XT_STRIDE);
    if (u<3) loadW(wsW1, 3*u+4, bwB); else loadW(wsW2, 1, bwB);
    gemmStep(3*u+2, bwC, acc, smem, XT_STRIDE);
    if (u<3) loadW(wsW1, 3*u+5, bwC); else loadW(wsW2, 2, bwC);
  }
  __syncthreads();                             // Xt dead

  // ---- h = lrelu(acc + b1) -> LDS [32][264 shorts], cvt_pk pairs ----
  {
    float bb[4];
    #pragma unroll
    for (int nt=0;nt<4;++nt) bb[nt] = b1[nq*64 + nt*16 + lrow];
    #pragma unroll
    for (int mt=0;mt<2;++mt)
      #pragma unroll
      for (int rg=0;rg<4;++rg) {
        const int row = mt*16 + lg*4 + rg;
        char* hb = smem + row*H_STRIDE + (nq*64 + lrow)*2;
        float v0 = lrelu(acc[mt][0][rg] + bb[0]);
        float v1 = lrelu(acc[mt][1][rg] + bb[1]);
        float v2 = lrelu(acc[mt][2][rg] + bb[2]);
        float v3 = lrelu(acc[mt][3][rg] + bb[3]);
        unsigned pA = cvt_pk_bf16(v0, v1), pB = cvt_pk_bf16(v2, v3);
        *(short*)(hb)      = (short)pA;
        *(short*)(hb + 32) = (short)(pA >> 16);
        *(short*)(hb + 64) = (short)pB;
        *(short*)(hb + 96) = (short)(pB >> 16);
      }
  }
  __syncthreads();

  // ---- GEMM2: h(32x256) @ W2, 8 K32 steps, dist-3 rotation ----
  f32x4 acc2[2][4];
  #pragma unroll
  for (int mt=0;mt<2;++mt)
    #pragma unroll
    for (int nt=0;nt<4;++nt) acc2[mt][nt] = (f32x4){0.f,0.f,0.f,0.f};
  gemmStep(0, bwA, acc2, smem, H_STRIDE); loadW(wsW2, 3, bwA);
  gemmStep(1, bwB, acc2, smem, H_STRIDE); loadW(wsW2, 4, bwB);
  gemmStep(2, bwC, acc2, smem, H_STRIDE); loadW(wsW2, 5, bwC);
  gemmStep(3, bwA, acc2, smem, H_STRIDE); loadW(wsW2, 6, bwA);
  gemmStep(4, bwB, acc2, smem, H_STRIDE); loadW(wsW2, 7, bwB);
  gemmStep(5, bwC, acc2, smem, H_STRIDE);
  gemmStep(6, bwA, acc2, smem, H_STRIDE);
  gemmStep(7, bwB, acc2, smem, H_STRIDE);

  // ---- epilogue ----
  {
    float bb[4];
    #pragma unroll
    for (int nt=0;nt<4;++nt) bb[nt] = b2[nq*64 + nt*16 + lrow];
    float* ob = out + ((size_t)b*N1 + row0) * H2;
    #pragma unroll
    for (int mt=0;mt<2;++mt)
      #pragma unroll
      for (int rg=0;rg<4;++rg) {
        const int row = mt*16 + lg*4 + rg;
        #pragma unroll
        for (int nt=0;nt<4;++nt) {
          const int col = nq*64 + nt*16 + lrow;
          ob[(size_t)row*H2 + col] = lrelu(acc2[mt][nt][rg] + bb[nt]);
        }
      }
  }
}

extern "C" void kernel_launch(void* const* d_in, const int* in_sizes, int n_in,
                              void* d_out, int out_size, void* d_ws, size_t ws_size,
                              hipStream_t stream) {
  const float* xyz1    = (const float*)d_in[0];
  const float* xyz2    = (const float*)d_in[1];
  const float* points1 = (const float*)d_in[2];
  const float* points2 = (const float*)d_in[3];
  const float* W1      = (const float*)d_in[4];
  const float* b1      = (const float*)d_in[5];
  const float* W2      = (const float*)d_in[6];
  const float* b2      = (const float*)d_in[7];
  float* out = (float*)d_out;

  hipLaunchKernelGGL(transform_w, dim3(80), dim3(256), 0, stream, W1, W2, (char*)d_ws);
  hipLaunchKernelGGL(fp_mfma, dim3(NB * (N1 / TM)), dim3(256), 0, stream,
                     xyz1, xyz2, points1, points2, (const char*)d_ws, b1, b2, out);
}